// Round 7
// baseline (110.747 us; speedup 1.0000x reference)
//
#include <hip/hip_runtime.h>
#include <hip/hip_bf16.h>

typedef unsigned short ushort;
typedef __attribute__((ext_vector_type(8))) short bf16x8;     // MFMA A/B frag (8 bf16)
typedef __attribute__((ext_vector_type(8))) unsigned short ushort8;
typedef __attribute__((ext_vector_type(4))) float f32x4;      // MFMA C/D frag
typedef __attribute__((ext_vector_type(4))) float float4v;

__device__ __forceinline__ ushort f2bf(float f) {
    union { float f; unsigned u; } v; v.f = f;
    unsigned r = v.u + 0x7FFFu + ((v.u >> 16) & 1u);
    return (ushort)(r >> 16);
}
__device__ __forceinline__ float bf2f(ushort u) {
    union { unsigned u; float f; } v; v.u = ((unsigned)u) << 16;
    return v.f;
}

// ---------------------------------------------------------------------------
// Merged LDS-tiled transpose + fp32->bf16 for all four weights.
// ---------------------------------------------------------------------------
__global__ __launch_bounds__(256) void transpose_all(
    const float* __restrict__ Wq, const float* __restrict__ Wk,
    const float* __restrict__ Wv, const float* __restrict__ Wo,
    ushort* __restrict__ Wq_t, ushort* __restrict__ Wk_t,
    ushort* __restrict__ Wv_t, ushort* __restrict__ Wo_t)
{
    __shared__ ushort t[32][33];
    int b = blockIdx.x;
    const float* src; ushort* dst; int K; int tb;
    if (b < 100)      { src = Wq; dst = Wq_t; K = 320; tb = b; }
    else if (b < 340) { src = Wk; dst = Wk_t; K = 768; tb = b - 100; }
    else if (b < 580) { src = Wv; dst = Wv_t; K = 768; tb = b - 340; }
    else              { src = Wo; dst = Wo_t; K = 320; tb = b - 580; }
    int tc = tb % 10, tr = tb / 10;
    int tx = threadIdx.x & 31, ty = threadIdx.x >> 5;
    #pragma unroll
    for (int p = 0; p < 4; ++p) {
        int k = tr * 32 + ty + p * 8, n = tc * 32 + tx;
        t[ty + p * 8][tx] = f2bf(src[(size_t)k * 320 + n]);
    }
    __syncthreads();
    #pragma unroll
    for (int p = 0; p < 4; ++p) {
        int n = tc * 32 + ty + p * 8, k = tr * 32 + tx;
        dst[(size_t)n * K + k] = t[tx][ty + p * 8];
    }
}

// ---------------------------------------------------------------------------
// Fused q-projection + split-K k/v-projection partials.  (unchanged)
// ---------------------------------------------------------------------------
__global__ __launch_bounds__(256) void gemm_qkv(
    const float* __restrict__ A, const ushort* __restrict__ Wq_t,
    const float* __restrict__ E, const ushort* __restrict__ Wk_t,
    const ushort* __restrict__ Wv_t,
    ushort* __restrict__ Qb, float* __restrict__ part)
{
    __shared__ ushort A_lds[2][64 * 40];
    __shared__ ushort B_lds[2][320 * 40];
    const int tid = threadIdx.x;
    const int w = tid >> 6, l = tid & 63;
    const int c15 = l & 15, khi = (l >> 4) * 8;
    const int r = tid >> 2, p = (tid & 3) * 8;
    const int rbase = (l >> 4) * 4;
    f32x4 acc[4][5] = {};
    const int bid = blockIdx.x;

    if (bid < 160) {
        const int mtile = bid % 10, mat = (bid / 10) & 1, ks = bid / 20;
        const int m0 = mtile * 64, kk0 = ks * 96;
        const ushort* Bt = mat ? Wv_t : Wk_t;
        const int m = m0 + r;
        const bool live = (m < 616);
        const float* Abase = E + (size_t)(live ? m : 0) * 768 + p;
        float4v a0 = {0,0,0,0}, a1 = {0,0,0,0};
        ushort8 breg[5];
        if (live) { a0 = *(const float4v*)(Abase + kk0); a1 = *(const float4v*)(Abase + kk0 + 4); }
        #pragma unroll
        for (int i = 0; i < 5; ++i) {
            int idx = tid + i * 256; int n = idx >> 2, q = (idx & 3) * 8;
            breg[i] = *(const ushort8*)(Bt + (size_t)n * 768 + kk0 + q);
        }
        {
            ushort* d = &A_lds[0][r * 40 + p];
            d[0]=f2bf(a0.x); d[1]=f2bf(a0.y); d[2]=f2bf(a0.z); d[3]=f2bf(a0.w);
            d[4]=f2bf(a1.x); d[5]=f2bf(a1.y); d[6]=f2bf(a1.z); d[7]=f2bf(a1.w);
            #pragma unroll
            for (int i = 0; i < 5; ++i) {
                int idx = tid + i * 256; int n = idx >> 2, q = (idx & 3) * 8;
                *(ushort8*)&B_lds[0][n * 40 + q] = breg[i];
            }
        }
        __syncthreads();
        for (int k = 0; k < 3; ++k) {
            const int cur = k & 1;
            if (k < 2) {
                int kk = kk0 + (k + 1) * 32;
                if (live) { a0 = *(const float4v*)(Abase + kk); a1 = *(const float4v*)(Abase + kk + 4); }
                #pragma unroll
                for (int i = 0; i < 5; ++i) {
                    int idx = tid + i * 256; int n = idx >> 2, q = (idx & 3) * 8;
                    breg[i] = *(const ushort8*)(Bt + (size_t)n * 768 + kk + q);
                }
            }
            bf16x8 a[4];
            #pragma unroll
            for (int mf = 0; mf < 4; ++mf)
                a[mf] = *(const bf16x8*)&A_lds[cur][(mf * 16 + c15) * 40 + khi];
            #pragma unroll
            for (int f = 0; f < 5; ++f) {
                bf16x8 b = *(const bf16x8*)&B_lds[cur][(w * 80 + f * 16 + c15) * 40 + khi];
                #pragma unroll
                for (int mf = 0; mf < 4; ++mf)
                    acc[mf][f] = __builtin_amdgcn_mfma_f32_16x16x32_bf16(a[mf], b, acc[mf][f], 0, 0, 0);
            }
            if (k < 2) {
                const int nxt = cur ^ 1;
                ushort* d = &A_lds[nxt][r * 40 + p];
                d[0]=f2bf(a0.x); d[1]=f2bf(a0.y); d[2]=f2bf(a0.z); d[3]=f2bf(a0.w);
                d[4]=f2bf(a1.x); d[5]=f2bf(a1.y); d[6]=f2bf(a1.z); d[7]=f2bf(a1.w);
                #pragma unroll
                for (int i = 0; i < 5; ++i) {
                    int idx = tid + i * 256; int n = idx >> 2, q = (idx & 3) * 8;
                    *(ushort8*)&B_lds[nxt][n * 40 + q] = breg[i];
                }
                __syncthreads();
            }
        }
        float* dst = part + (size_t)(mat * 8 + ks) * 640 * 320;
        #pragma unroll
        for (int mf = 0; mf < 4; ++mf)
            #pragma unroll
            for (int f = 0; f < 5; ++f) {
                int col = w * 80 + f * 16 + c15;
                #pragma unroll
                for (int rr = 0; rr < 4; ++rr)
                    dst[(size_t)(m0 + mf * 16 + rbase + rr) * 320 + col] = acc[mf][f][rr];
            }
    } else {
        const int m0 = (bid - 160) * 64;
        const float* Abase = A + (size_t)(m0 + r) * 320 + p;
        float4v a0, a1; ushort8 breg[5];
        a0 = *(const float4v*)(Abase + 0);
        a1 = *(const float4v*)(Abase + 4);
        #pragma unroll
        for (int i = 0; i < 5; ++i) {
            int idx = tid + i * 256; int n = idx >> 2, q = (idx & 3) * 8;
            breg[i] = *(const ushort8*)(Wq_t + (size_t)n * 320 + q);
        }
        {
            ushort* d = &A_lds[0][r * 40 + p];
            d[0]=f2bf(a0.x); d[1]=f2bf(a0.y); d[2]=f2bf(a0.z); d[3]=f2bf(a0.w);
            d[4]=f2bf(a1.x); d[5]=f2bf(a1.y); d[6]=f2bf(a1.z); d[7]=f2bf(a1.w);
            #pragma unroll
            for (int i = 0; i < 5; ++i) {
                int idx = tid + i * 256; int n = idx >> 2, q = (idx & 3) * 8;
                *(ushort8*)&B_lds[0][n * 40 + q] = breg[i];
            }
        }
        __syncthreads();
        for (int k = 0; k < 10; ++k) {
            const int cur = k & 1;
            if (k < 9) {
                int kk = (k + 1) * 32;
                a0 = *(const float4v*)(Abase + kk);
                a1 = *(const float4v*)(Abase + kk + 4);
                #pragma unroll
                for (int i = 0; i < 5; ++i) {
                    int idx = tid + i * 256; int n = idx >> 2, q = (idx & 3) * 8;
                    breg[i] = *(const ushort8*)(Wq_t + (size_t)n * 320 + kk + q);
                }
            }
            bf16x8 a[4];
            #pragma unroll
            for (int mf = 0; mf < 4; ++mf)
                a[mf] = *(const bf16x8*)&A_lds[cur][(mf * 16 + c15) * 40 + khi];
            #pragma unroll
            for (int f = 0; f < 5; ++f) {
                bf16x8 b = *(const bf16x8*)&B_lds[cur][(w * 80 + f * 16 + c15) * 40 + khi];
                #pragma unroll
                for (int mf = 0; mf < 4; ++mf)
                    acc[mf][f] = __builtin_amdgcn_mfma_f32_16x16x32_bf16(a[mf], b, acc[mf][f], 0, 0, 0);
            }
            if (k < 9) {
                const int nxt = cur ^ 1;
                ushort* d = &A_lds[nxt][r * 40 + p];
                d[0]=f2bf(a0.x); d[1]=f2bf(a0.y); d[2]=f2bf(a0.z); d[3]=f2bf(a0.w);
                d[4]=f2bf(a1.x); d[5]=f2bf(a1.y); d[6]=f2bf(a1.z); d[7]=f2bf(a1.w);
                #pragma unroll
                for (int i = 0; i < 5; ++i) {
                    int idx = tid + i * 256; int n = idx >> 2, q = (idx & 3) * 8;
                    *(ushort8*)&B_lds[nxt][n * 40 + q] = breg[i];
                }
                __syncthreads();
            }
        }
        #pragma unroll
        for (int mf = 0; mf < 4; ++mf)
            #pragma unroll
            for (int f = 0; f < 5; ++f) {
                int col = w * 80 + f * 16 + c15;
                #pragma unroll
                for (int rr = 0; rr < 4; ++rr)
                    Qb[(size_t)(m0 + mf * 16 + rbase + rr) * 320 + col] = f2bf(acc[mf][f][rr]);
            }
    }
}

// ---------------------------------------------------------------------------
// Reduce 8 split-K partials -> Kb (row-major) / VVt (transposed, s padded 80).
// ---------------------------------------------------------------------------
__global__ __launch_bounds__(256) void kv_reduce(
    const float* __restrict__ part, ushort* __restrict__ Kb, ushort* __restrict__ VVt)
{
    int idx = blockIdx.x * 256 + threadIdx.x;
    if (idx >= 616 * 320) return;
    int mat = blockIdx.y;
    int row = idx / 320, col = idx - row * 320;
    float s = 0.f;
    #pragma unroll
    for (int ks = 0; ks < 8; ++ks)
        s += part[((size_t)(mat * 8 + ks) * 640 + row) * 320 + col];
    ushort b = f2bf(s);
    if (mat == 0) {
        Kb[(size_t)row * 320 + col] = b;
    } else {
        int bt = row / 77, ss = row - bt * 77;
        VVt[((size_t)bt * 320 + col) * 80 + ss] = b;
    }
}

// ---------------------------------------------------------------------------
// v'^T[p][c][m] = sum_e mapper[p][m][e] * V^T[5+p][c][e]
// ---------------------------------------------------------------------------
__global__ void vprime_k(const float* __restrict__ mapper, const ushort* __restrict__ VVt,
                         ushort* __restrict__ VPt)
{
    int pm = blockIdx.x;            // p*77 + m
    int p = pm / 77, m = pm - p * 77;
    __shared__ float mp[77];
    int tid = threadIdx.x;          // 320 threads, one per channel c
    if (tid < 77) mp[tid] = mapper[(size_t)pm * 77 + tid];
    __syncthreads();
    const ushort* vrow = VVt + ((size_t)(5 + p) * 320 + tid) * 80;
    float acc = 0.f;
    for (int e = 0; e < 77; ++e) acc += mp[e] * bf2f(vrow[e]);
    VPt[((size_t)p * 320 + tid) * 80 + m] = f2bf(acc);
}

// ---------------------------------------------------------------------------
// FUSED attention + out-projection. grid = (T/64, BT=8), 256 thr (4 waves).
// Per block: 64 output rows of batch bt. Loop h=0..7: stage Q/K/V, QK^T,
// softmax, PV -> AO_lds[64][328] bf16. Then out = AO @ Wo_t^T + bias (f32).
// NaN-safety rule: every LDS cell an MFMA reads is either freshly staged or
// explicitly zeroed — V pad (rows 0..39 cols 80..103, rows 40..47 all cols)
// zeroed one-time; VVt/VPt s-pad (77..79) masked to zero at staging.
// ---------------------------------------------------------------------------
#define ATT_SCALE 0.15811388300841897f   // 1/sqrt(40)
__global__ __launch_bounds__(256) void attn_out_k(
    const ushort* __restrict__ Q, const ushort* __restrict__ K,
    const ushort* __restrict__ VVt, const ushort* __restrict__ VPt,
    const ushort* __restrict__ Wo_t, const float* __restrict__ bias,
    float* __restrict__ out)
{
    __shared__ __align__(16) ushort smem[20992 + 25600];   // 93,184 B
    ushort* AO_lds = smem;                      // [64][328]
    ushort* W_lds  = smem + 20992;              // [2][320*40]  (outproj phase)
    ushort* Q_lds  = smem + 20992;              // [64][72]     (attn phase)
    ushort* K_lds  = Q_lds + 64 * 72;           // [80][72]
    ushort* V_lds  = K_lds + 80 * 72;           // [48][104]
    ushort* P_lds  = V_lds + 48 * 104;          // [64][104]

    const int tid = threadIdx.x;
    const int w = tid >> 6, l = tid & 63;
    const int c15 = l & 15, khi = (l >> 4) * 8;
    const int rbase = (l >> 4) * 4;
    const int bt = blockIdx.y, t0 = blockIdx.x * 64;
    const int qb = (bt < 5) ? bt : 4;
    const ushort* Vbase = (bt < 5) ? (VVt + (size_t)bt * 320 * 80)
                                   : (VPt + (size_t)(bt - 5) * 320 * 80);
    const ushort8 z8 = {0,0,0,0,0,0,0,0};

    // ---- one-time zero of all pad regions (disjoint from staged regions) ----
    {   // Q k-pad 40..71 (64 rows x 4 chunks)
        int r = tid >> 2, c = tid & 3;
        *(ushort8*)&Q_lds[r * 72 + 40 + c * 8] = z8;
    }
    for (int i = tid; i < 320; i += 256) {      // K k-pad 40..71 (80 rows x 4)
        int s = i >> 2, c = i & 3;
        *(ushort8*)&K_lds[s * 72 + 40 + c * 8] = z8;
    }
    for (int i = tid; i < 15; i += 256) {       // K rows 77..79, k 0..39
        int s = 77 + i / 5, c = i - 5 * (i / 5);
        *(ushort8*)&K_lds[s * 72 + c * 8] = z8;
    }
    for (int i = tid; i < 224; i += 256) {      // V pad: rows 0..39 cols 80..103
        int dc, cc;                             //        + rows 40..47 all cols
        if (i < 120) { dc = i / 3; cc = 10 + (i - 3 * dc); }
        else { int j = i - 120; dc = 40 + j / 13; cc = j - 13 * (j / 13); }
        *(ushort8*)&V_lds[dc * 104 + cc * 8] = z8;
    }
    for (int i = tid; i < 192; i += 256) {      // P cols 80..103 (64 x 3)
        int r = i / 3, c = i - 3 * r;
        *(ushort8*)&P_lds[r * 104 + 80 + c * 8] = z8;
    }

    // ---- per-head attention ----
    for (int h = 0; h < 8; ++h) {
        for (int i = tid; i < 320; i += 256) {          // Q_h: 64 rows x 5 chunks
            int r = i / 5, c = i - 5 * r;
            *(ushort8*)&Q_lds[r * 72 + c * 8] =
                *(const ushort8*)(Q + (size_t)(qb * 4096 + t0 + r) * 320 + h * 40 + c * 8);
        }
        for (int i = tid; i < 385; i += 256) {          // K_h: 77 rows x 5 chunks
            int s = i / 5, c = i - 5 * s;
            *(ushort8*)&K_lds[s * 72 + c * 8] =
                *(const ushort8*)(K + (size_t)(qb * 77 + s) * 320 + h * 40 + c * 8);
        }
        for (int i = tid; i < 400; i += 256) {          // V_h^T: 40 rows x 10 chunks
            int dc = i / 10, c = i - 10 * dc;
            ushort8 v = *(const ushort8*)(Vbase + ((size_t)h * 40 + dc) * 80 + c * 8);
            if (c == 9) { v[5] = 0; v[6] = 0; v[7] = 0; }   // VVt/VPt s-pad 77..79
            *(ushort8*)&V_lds[dc * 104 + c * 8] = v;
        }
        __syncthreads();

        // QK^T : rows 16w.., cols 0..79 (5 frags), K-dim 64 (2 steps)
        f32x4 sacc[5] = {};
        bf16x8 qa[2];
        #pragma unroll
        for (int kt = 0; kt < 2; ++kt)
            qa[kt] = *(const bf16x8*)&Q_lds[(w * 16 + c15) * 72 + kt * 32 + khi];
        #pragma unroll
        for (int f = 0; f < 5; ++f)
            #pragma unroll
            for (int kt = 0; kt < 2; ++kt) {
                bf16x8 kb = *(const bf16x8*)&K_lds[(f * 16 + c15) * 72 + kt * 32 + khi];
                sacc[f] = __builtin_amdgcn_mfma_f32_16x16x32_bf16(qa[kt], kb, sacc[f], 0, 0, 0);
            }

        // masked softmax (per C-row; 16-lane shuffle reduce)
        float pv[5][4];
        #pragma unroll
        for (int r = 0; r < 4; ++r) {
            float mx = -1e30f;
            #pragma unroll
            for (int f = 0; f < 5; ++f) {
                float vs = sacc[f][r] * ATT_SCALE;
                bool valid = (f < 4) || (c15 < 13);     // col = 16f + c15 < 77
                pv[f][r] = valid ? vs : -1e30f;
                mx = fmaxf(mx, pv[f][r]);
            }
            #pragma unroll
            for (int d = 1; d < 16; d <<= 1) mx = fmaxf(mx, __shfl_xor(mx, d));
            float sum = 0.f;
            #pragma unroll
            for (int f = 0; f < 5; ++f) {
                float e = (pv[f][r] > -1e29f) ? __expf(pv[f][r] - mx) : 0.f;
                pv[f][r] = e; sum += e;
            }
            #pragma unroll
            for (int d = 1; d < 16; d <<= 1) sum += __shfl_xor(sum, d);
            float inv = 1.f / sum;
            #pragma unroll
            for (int f = 0; f < 5; ++f) pv[f][r] *= inv;
        }
        #pragma unroll
        for (int r = 0; r < 4; ++r)
            #pragma unroll
            for (int f = 0; f < 5; ++f)
                P_lds[(w * 16 + rbase + r) * 104 + f * 16 + c15] = f2bf(pv[f][r]);
        __syncthreads();

        // PV: out rows 16w.., dcols 0..47 (3 frags), K-dim 96 (3 steps)
        bf16x8 pa[3];
        #pragma unroll
        for (int kt = 0; kt < 3; ++kt)
            pa[kt] = *(const bf16x8*)&P_lds[(w * 16 + c15) * 104 + kt * 32 + khi];
        f32x4 oacc[3] = {};
        #pragma unroll
        for (int f = 0; f < 3; ++f)
            #pragma unroll
            for (int kt = 0; kt < 3; ++kt) {
                bf16x8 vb = *(const bf16x8*)&V_lds[(f * 16 + c15) * 104 + kt * 32 + khi];
                oacc[f] = __builtin_amdgcn_mfma_f32_16x16x32_bf16(pa[kt], vb, oacc[f], 0, 0, 0);
            }
        #pragma unroll
        for (int f = 0; f < 3; ++f) {
            int col = f * 16 + c15;
            if (col < 40) {
                #pragma unroll
                for (int r = 0; r < 4; ++r)
                    AO_lds[(size_t)(w * 16 + rbase + r) * 328 + h * 40 + col] = f2bf(oacc[f][r]);
            }
        }
        __syncthreads();   // AO writes done; Q/K/V/P free for restaging (or W)
    }

    // ---- out-projection: out[64x320] = AO_lds @ Wo_t^T + bias ----
    f32x4 acc[4][5] = {};
    ushort8 breg[5];
    #pragma unroll
    for (int i = 0; i < 5; ++i) {
        int idx = tid + i * 256; int n = idx >> 2, q = (idx & 3) * 8;
        breg[i] = *(const ushort8*)(Wo_t + (size_t)n * 320 + q);
    }
    #pragma unroll
    for (int i = 0; i < 5; ++i) {
        int idx = tid + i * 256; int n = idx >> 2, q = (idx & 3) * 8;
        *(ushort8*)&W_lds[n * 40 + q] = breg[i];
    }
    __syncthreads();
    for (int k = 0; k < 10; ++k) {
        const int cur = k & 1;
        if (k < 9) {
            int kk = (k + 1) * 32;
            #pragma unroll
            for (int i = 0; i < 5; ++i) {
                int idx = tid + i * 256; int n = idx >> 2, q = (idx & 3) * 8;
                breg[i] = *(const ushort8*)(Wo_t + (size_t)n * 320 + kk + q);
            }
        }
        bf16x8 a[4];
        #pragma unroll
        for (int mf = 0; mf < 4; ++mf)
            a[mf] = *(const bf16x8*)&AO_lds[(size_t)(mf * 16 + c15) * 328 + k * 32 + khi];
        #pragma unroll
        for (int f = 0; f < 5; ++f) {
            bf16x8 b = *(const bf16x8*)&W_lds[(cur * 12800) + (w * 80 + f * 16 + c15) * 40 + khi];
            #pragma unroll
            for (int mf = 0; mf < 4; ++mf)
                acc[mf][f] = __builtin_amdgcn_mfma_f32_16x16x32_bf16(a[mf], b, acc[mf][f], 0, 0, 0);
        }
        if (k < 9) {
            const int nxt = cur ^ 1;
            #pragma unroll
            for (int i = 0; i < 5; ++i) {
                int idx = tid + i * 256; int n = idx >> 2, q = (idx & 3) * 8;
                *(ushort8*)&W_lds[(nxt * 12800) + n * 40 + q] = breg[i];
            }
            __syncthreads();
        }
    }
    #pragma unroll
    for (int mf = 0; mf < 4; ++mf)
        #pragma unroll
        for (int f = 0; f < 5; ++f) {
            int col = w * 80 + f * 16 + c15;
            #pragma unroll
            for (int rr = 0; rr < 4; ++rr)
                out[(size_t)(bt * 4096 + t0 + mf * 16 + rbase + rr) * 320 + col]
                    = acc[mf][f][rr] + bias[col];
        }
}

// ---------------------------------------------------------------------------
extern "C" void kernel_launch(void* const* d_in, const int* in_sizes, int n_in,
                              void* d_out, int out_size, void* d_ws, size_t ws_size,
                              hipStream_t stream) {
    (void)in_sizes; (void)n_in; (void)out_size; (void)ws_size;
    const float* hs     = (const float*)d_in[0];   // (8,4096,320)
    const float* ehs    = (const float*)d_in[1];   // (8,77,768)
    const float* mapper = (const float*)d_in[2];   // (3,77,77)
    const float* Wq     = (const float*)d_in[3];   // (320,320)
    const float* Wk     = (const float*)d_in[4];   // (768,320)
    const float* Wv     = (const float*)d_in[5];   // (768,320)
    const float* Wo     = (const float*)d_in[6];   // (320,320)
    const float* bo     = (const float*)d_in[7];   // (320,)
    float* out = (float*)d_out;

    ushort* ws   = (ushort*)d_ws;
    ushort* Wq_t = ws;                             // 320*320
    ushort* Wk_t = Wq_t + 320 * 320;               // 320*768
    ushort* Wv_t = Wk_t + 320 * 768;
    ushort* Wo_t = Wv_t + 320 * 768;               // 320*320
    ushort* Qb   = Wo_t + 320 * 320;               // 20480*320
    ushort* Kb   = Qb + 20480 * 320;               // 616*320
    ushort* VVt  = Kb + 616 * 320;                 // 8*320*80  (V^T, s padded 80)
    ushort* VPt  = VVt + 8 * 320 * 80;             // 3*320*80  (V'^T)
    float*  part = (float*)(VPt + 3 * 320 * 80);   // 16*640*320 f32 = 13.1 MB

    transpose_all<<<680, 256, 0, stream>>>(Wq, Wk, Wv, Wo, Wq_t, Wk_t, Wv_t, Wo_t);
    gemm_qkv<<<480, 256, 0, stream>>>(hs, Wq_t, ehs, Wk_t, Wv_t, Qb, part);
    kv_reduce<<<dim3(770, 2), 256, 0, stream>>>(part, Kb, VVt);
    vprime_k<<<231, 320, 0, stream>>>(mapper, VVt, VPt);
    attn_out_k<<<dim3(64, 8), 256, 0, stream>>>(Qb, Kb, VVt, VPt, Wo_t, bo, out);
}

// Round 8
// 77.992 us; speedup vs baseline: 1.4200x; 1.4200x over previous
//
#include <hip/hip_runtime.h>
#include <hip/hip_bf16.h>

typedef unsigned short ushort;
typedef __attribute__((ext_vector_type(8))) short bf16x8;     // MFMA A/B frag (8 bf16)
typedef __attribute__((ext_vector_type(8))) unsigned short ushort8;
typedef __attribute__((ext_vector_type(4))) float f32x4;      // MFMA C/D frag
typedef __attribute__((ext_vector_type(4))) float float4v;

__device__ __forceinline__ ushort f2bf(float f) {
    union { float f; unsigned u; } v; v.f = f;
    unsigned r = v.u + 0x7FFFu + ((v.u >> 16) & 1u);
    return (ushort)(r >> 16);
}
__device__ __forceinline__ float bf2f(ushort u) {
    union { unsigned u; float f; } v; v.u = ((unsigned)u) << 16;
    return v.f;
}

// ---------------------------------------------------------------------------
// Merged LDS-tiled transpose + fp32->bf16 for all four weights.
// ---------------------------------------------------------------------------
__global__ __launch_bounds__(256) void transpose_all(
    const float* __restrict__ Wq, const float* __restrict__ Wk,
    const float* __restrict__ Wv, const float* __restrict__ Wo,
    ushort* __restrict__ Wq_t, ushort* __restrict__ Wk_t,
    ushort* __restrict__ Wv_t, ushort* __restrict__ Wo_t)
{
    __shared__ ushort t[32][33];
    int b = blockIdx.x;
    const float* src; ushort* dst; int K; int tb;
    if (b < 100)      { src = Wq; dst = Wq_t; K = 320; tb = b; }
    else if (b < 340) { src = Wk; dst = Wk_t; K = 768; tb = b - 100; }
    else if (b < 580) { src = Wv; dst = Wv_t; K = 768; tb = b - 340; }
    else              { src = Wo; dst = Wo_t; K = 320; tb = b - 580; }
    int tc = tb % 10, tr = tb / 10;
    int tx = threadIdx.x & 31, ty = threadIdx.x >> 5;
    #pragma unroll
    for (int p = 0; p < 4; ++p) {
        int k = tr * 32 + ty + p * 8, n = tc * 32 + tx;
        t[ty + p * 8][tx] = f2bf(src[(size_t)k * 320 + n]);
    }
    __syncthreads();
    #pragma unroll
    for (int p = 0; p < 4; ++p) {
        int n = tc * 32 + ty + p * 8, k = tr * 32 + tx;
        dst[(size_t)n * K + k] = t[tx][ty + p * 8];
    }
}

// ---------------------------------------------------------------------------
// Fused q-projection + split-K k/v-projection partials.  (unchanged)
// ---------------------------------------------------------------------------
__global__ __launch_bounds__(256) void gemm_qkv(
    const float* __restrict__ A, const ushort* __restrict__ Wq_t,
    const float* __restrict__ E, const ushort* __restrict__ Wk_t,
    const ushort* __restrict__ Wv_t,
    ushort* __restrict__ Qb, float* __restrict__ part)
{
    __shared__ ushort A_lds[2][64 * 40];
    __shared__ ushort B_lds[2][320 * 40];
    const int tid = threadIdx.x;
    const int w = tid >> 6, l = tid & 63;
    const int c15 = l & 15, khi = (l >> 4) * 8;
    const int r = tid >> 2, p = (tid & 3) * 8;
    const int rbase = (l >> 4) * 4;
    f32x4 acc[4][5] = {};
    const int bid = blockIdx.x;

    if (bid < 160) {
        const int mtile = bid % 10, mat = (bid / 10) & 1, ks = bid / 20;
        const int m0 = mtile * 64, kk0 = ks * 96;
        const ushort* Bt = mat ? Wv_t : Wk_t;
        const int m = m0 + r;
        const bool live = (m < 616);
        const float* Abase = E + (size_t)(live ? m : 0) * 768 + p;
        float4v a0 = {0,0,0,0}, a1 = {0,0,0,0};
        ushort8 breg[5];
        if (live) { a0 = *(const float4v*)(Abase + kk0); a1 = *(const float4v*)(Abase + kk0 + 4); }
        #pragma unroll
        for (int i = 0; i < 5; ++i) {
            int idx = tid + i * 256; int n = idx >> 2, q = (idx & 3) * 8;
            breg[i] = *(const ushort8*)(Bt + (size_t)n * 768 + kk0 + q);
        }
        {
            ushort* d = &A_lds[0][r * 40 + p];
            d[0]=f2bf(a0.x); d[1]=f2bf(a0.y); d[2]=f2bf(a0.z); d[3]=f2bf(a0.w);
            d[4]=f2bf(a1.x); d[5]=f2bf(a1.y); d[6]=f2bf(a1.z); d[7]=f2bf(a1.w);
            #pragma unroll
            for (int i = 0; i < 5; ++i) {
                int idx = tid + i * 256; int n = idx >> 2, q = (idx & 3) * 8;
                *(ushort8*)&B_lds[0][n * 40 + q] = breg[i];
            }
        }
        __syncthreads();
        for (int k = 0; k < 3; ++k) {
            const int cur = k & 1;
            if (k < 2) {
                int kk = kk0 + (k + 1) * 32;
                if (live) { a0 = *(const float4v*)(Abase + kk); a1 = *(const float4v*)(Abase + kk + 4); }
                #pragma unroll
                for (int i = 0; i < 5; ++i) {
                    int idx = tid + i * 256; int n = idx >> 2, q = (idx & 3) * 8;
                    breg[i] = *(const ushort8*)(Bt + (size_t)n * 768 + kk + q);
                }
            }
            bf16x8 a[4];
            #pragma unroll
            for (int mf = 0; mf < 4; ++mf)
                a[mf] = *(const bf16x8*)&A_lds[cur][(mf * 16 + c15) * 40 + khi];
            #pragma unroll
            for (int f = 0; f < 5; ++f) {
                bf16x8 b = *(const bf16x8*)&B_lds[cur][(w * 80 + f * 16 + c15) * 40 + khi];
                #pragma unroll
                for (int mf = 0; mf < 4; ++mf)
                    acc[mf][f] = __builtin_amdgcn_mfma_f32_16x16x32_bf16(a[mf], b, acc[mf][f], 0, 0, 0);
            }
            if (k < 2) {
                const int nxt = cur ^ 1;
                ushort* d = &A_lds[nxt][r * 40 + p];
                d[0]=f2bf(a0.x); d[1]=f2bf(a0.y); d[2]=f2bf(a0.z); d[3]=f2bf(a0.w);
                d[4]=f2bf(a1.x); d[5]=f2bf(a1.y); d[6]=f2bf(a1.z); d[7]=f2bf(a1.w);
                #pragma unroll
                for (int i = 0; i < 5; ++i) {
                    int idx = tid + i * 256; int n = idx >> 2, q = (idx & 3) * 8;
                    *(ushort8*)&B_lds[nxt][n * 40 + q] = breg[i];
                }
                __syncthreads();
            }
        }
        float* dst = part + (size_t)(mat * 8 + ks) * 640 * 320;
        #pragma unroll
        for (int mf = 0; mf < 4; ++mf)
            #pragma unroll
            for (int f = 0; f < 5; ++f) {
                int col = w * 80 + f * 16 + c15;
                #pragma unroll
                for (int rr = 0; rr < 4; ++rr)
                    dst[(size_t)(m0 + mf * 16 + rbase + rr) * 320 + col] = acc[mf][f][rr];
            }
    } else {
        const int m0 = (bid - 160) * 64;
        const float* Abase = A + (size_t)(m0 + r) * 320 + p;
        float4v a0, a1; ushort8 breg[5];
        a0 = *(const float4v*)(Abase + 0);
        a1 = *(const float4v*)(Abase + 4);
        #pragma unroll
        for (int i = 0; i < 5; ++i) {
            int idx = tid + i * 256; int n = idx >> 2, q = (idx & 3) * 8;
            breg[i] = *(const ushort8*)(Wq_t + (size_t)n * 320 + q);
        }
        {
            ushort* d = &A_lds[0][r * 40 + p];
            d[0]=f2bf(a0.x); d[1]=f2bf(a0.y); d[2]=f2bf(a0.z); d[3]=f2bf(a0.w);
            d[4]=f2bf(a1.x); d[5]=f2bf(a1.y); d[6]=f2bf(a1.z); d[7]=f2bf(a1.w);
            #pragma unroll
            for (int i = 0; i < 5; ++i) {
                int idx = tid + i * 256; int n = idx >> 2, q = (idx & 3) * 8;
                *(ushort8*)&B_lds[0][n * 40 + q] = breg[i];
            }
        }
        __syncthreads();
        for (int k = 0; k < 10; ++k) {
            const int cur = k & 1;
            if (k < 9) {
                int kk = (k + 1) * 32;
                a0 = *(const float4v*)(Abase + kk);
                a1 = *(const float4v*)(Abase + kk + 4);
                #pragma unroll
                for (int i = 0; i < 5; ++i) {
                    int idx = tid + i * 256; int n = idx >> 2, q = (idx & 3) * 8;
                    breg[i] = *(const ushort8*)(Wq_t + (size_t)n * 320 + kk + q);
                }
            }
            bf16x8 a[4];
            #pragma unroll
            for (int mf = 0; mf < 4; ++mf)
                a[mf] = *(const bf16x8*)&A_lds[cur][(mf * 16 + c15) * 40 + khi];
            #pragma unroll
            for (int f = 0; f < 5; ++f) {
                bf16x8 b = *(const bf16x8*)&B_lds[cur][(w * 80 + f * 16 + c15) * 40 + khi];
                #pragma unroll
                for (int mf = 0; mf < 4; ++mf)
                    acc[mf][f] = __builtin_amdgcn_mfma_f32_16x16x32_bf16(a[mf], b, acc[mf][f], 0, 0, 0);
            }
            if (k < 9) {
                const int nxt = cur ^ 1;
                ushort* d = &A_lds[nxt][r * 40 + p];
                d[0]=f2bf(a0.x); d[1]=f2bf(a0.y); d[2]=f2bf(a0.z); d[3]=f2bf(a0.w);
                d[4]=f2bf(a1.x); d[5]=f2bf(a1.y); d[6]=f2bf(a1.z); d[7]=f2bf(a1.w);
                #pragma unroll
                for (int i = 0; i < 5; ++i) {
                    int idx = tid + i * 256; int n = idx >> 2, q = (idx & 3) * 8;
                    *(ushort8*)&B_lds[nxt][n * 40 + q] = breg[i];
                }
                __syncthreads();
            }
        }
        #pragma unroll
        for (int mf = 0; mf < 4; ++mf)
            #pragma unroll
            for (int f = 0; f < 5; ++f) {
                int col = w * 80 + f * 16 + c15;
                #pragma unroll
                for (int rr = 0; rr < 4; ++rr)
                    Qb[(size_t)(m0 + mf * 16 + rbase + rr) * 320 + col] = f2bf(acc[mf][f][rr]);
            }
    }
}

// ---------------------------------------------------------------------------
// Reduce 8 split-K partials -> Kb (row-major) / VVt (transposed, s padded 80).
// ---------------------------------------------------------------------------
__global__ __launch_bounds__(256) void kv_reduce(
    const float* __restrict__ part, ushort* __restrict__ Kb, ushort* __restrict__ VVt)
{
    int idx = blockIdx.x * 256 + threadIdx.x;
    if (idx >= 616 * 320) return;
    int mat = blockIdx.y;
    int row = idx / 320, col = idx - row * 320;
    float s = 0.f;
    #pragma unroll
    for (int ks = 0; ks < 8; ++ks)
        s += part[((size_t)(mat * 8 + ks) * 640 + row) * 320 + col];
    ushort b = f2bf(s);
    if (mat == 0) {
        Kb[(size_t)row * 320 + col] = b;
    } else {
        int bt = row / 77, ss = row - bt * 77;
        VVt[((size_t)bt * 320 + col) * 80 + ss] = b;
    }
}

// ---------------------------------------------------------------------------
// v'^T[p][c][m] = sum_e mapper[p][m][e] * V^T[5+p][c][e]
// ---------------------------------------------------------------------------
__global__ void vprime_k(const float* __restrict__ mapper, const ushort* __restrict__ VVt,
                         ushort* __restrict__ VPt)
{
    int pm = blockIdx.x;            // p*77 + m
    int p = pm / 77, m = pm - p * 77;
    __shared__ float mp[77];
    int tid = threadIdx.x;          // 320 threads, one per channel c
    if (tid < 77) mp[tid] = mapper[(size_t)pm * 77 + tid];
    __syncthreads();
    const ushort* vrow = VVt + ((size_t)(5 + p) * 320 + tid) * 80;
    float acc = 0.f;
    for (int e = 0; e < 77; ++e) acc += mp[e] * bf2f(vrow[e]);
    VPt[((size_t)p * 320 + tid) * 80 + m] = f2bf(acc);
}

// ---------------------------------------------------------------------------
// FUSED attention + out-projection. grid = (T/64, BT=8), 256 thr (4 waves).
// LDS 74 KB -> 2 blocks/CU. K and V time-share one 11.5 KB region (K during
// QK^T, V during PV). Next-head Q/K/V prefetched into registers under compute.
// NaN-safety: at h=0 the K pass covers the whole shared region (data+zeros);
// thereafter all "pad" reads are finite leftovers ×0, or feed discarded cols.
// ---------------------------------------------------------------------------
#define ATT_SCALE 0.15811388300841897f   // 1/sqrt(40)
__global__ __launch_bounds__(256) void attn_out_k(
    const ushort* __restrict__ Q, const ushort* __restrict__ K,
    const ushort* __restrict__ VVt, const ushort* __restrict__ VPt,
    const ushort* __restrict__ Wo_t, const float* __restrict__ bias,
    float* __restrict__ out)
{
    __shared__ __align__(16) ushort smem[38016];   // 76,032 B
    ushort* AO_lds = smem;                  // [64][328]          (20992)
    ushort* Q_lds  = smem + 20992;          // [64][72]           (4608)
    ushort* KV_lds = smem + 25600;          // K:[80][72] / V:[48][104] (5760)
    ushort* P_lds  = smem + 31360;          // [64][104]          (6656)
    ushort* W_lds  = smem + 20992;          // [320][40] outproj  (12800, aliases)

    const int tid = threadIdx.x;
    const int w = tid >> 6, l = tid & 63;
    const int c15 = l & 15, khi = (l >> 4) * 8;
    const int rbase = (l >> 4) * 4;
    const int bt = blockIdx.y, t0 = blockIdx.x * 64;
    const int qb = (bt < 5) ? bt : 4;
    const ushort* Vbase = (bt < 5) ? (VVt + (size_t)bt * 320 * 80)
                                   : (VPt + (size_t)(bt - 5) * 320 * 80);
    const ushort8 z8 = {0,0,0,0,0,0,0,0};

    // ---- one-time zeros in exclusive regions ----
    {   // Q k-pad 40..71 (64 rows x 4 chunks)
        int r = tid >> 2, c = tid & 3;
        *(ushort8*)&Q_lds[r * 72 + 40 + c * 8] = z8;
    }
    for (int i = tid; i < 192; i += 256) {      // P cols 80..103 (64 x 3)
        int r = i / 3, c = i - 3 * r;
        *(ushort8*)&P_lds[r * 104 + 80 + c * 8] = z8;
    }

    // ---- prefetch registers (head 0) ----
    ushort8 qreg[2], kreg[2], vreg[2];
    #pragma unroll
    for (int j = 0; j < 2; ++j) {
        int idx = tid + j * 256;
        if (idx < 320) {
            int r = idx / 5, c = idx - 5 * r;
            qreg[j] = *(const ushort8*)(Q + (size_t)(qb * 4096 + t0 + r) * 320 + c * 8);
        }
        if (idx < 385) {
            int s = idx / 5, c = idx - 5 * s;
            kreg[j] = *(const ushort8*)(K + (size_t)(qb * 77 + s) * 320 + c * 8);
        }
        if (idx < 400) {
            int dc = idx / 10, c = idx - 10 * dc;
            ushort8 v = *(const ushort8*)(Vbase + (size_t)dc * 80 + c * 8);
            if (c == 9) { v[5] = 0; v[6] = 0; v[7] = 0; }
            vreg[j] = v;
        }
    }

    // ---- per-head attention ----
    for (int h = 0; h < 8; ++h) {
        // phase A: write Q,K from regs
        #pragma unroll
        for (int j = 0; j < 2; ++j) {
            int idx = tid + j * 256;
            if (idx < 320) {
                int r = idx / 5, c = idx - 5 * r;
                *(ushort8*)&Q_lds[r * 72 + c * 8] = qreg[j];
            }
            if (idx < 385) {
                int s = idx / 5, c = idx - 5 * s;
                *(ushort8*)&KV_lds[s * 72 + c * 8] = kreg[j];
            }
        }
        if (h == 0) {   // cover K region pads once (finite forever after)
            for (int i = tid; i < 320; i += 256) {      // kd 40..71 (80 x 4)
                int s = i >> 2, c = i & 3;
                *(ushort8*)&KV_lds[s * 72 + 40 + c * 8] = z8;
            }
            for (int i = tid; i < 15; i += 256) {       // s 77..79, kd 0..39
                int s = 77 + i / 5, c = i - 5 * (i / 5);
                *(ushort8*)&KV_lds[s * 72 + c * 8] = z8;
            }
        }
        __syncthreads();

        if (h < 7) {    // prefetch next head's Q/K (lands under QK+softmax+PV)
            #pragma unroll
            for (int j = 0; j < 2; ++j) {
                int idx = tid + j * 256;
                if (idx < 320) {
                    int r = idx / 5, c = idx - 5 * r;
                    qreg[j] = *(const ushort8*)(Q + (size_t)(qb * 4096 + t0 + r) * 320 + (h + 1) * 40 + c * 8);
                }
                if (idx < 385) {
                    int s = idx / 5, c = idx - 5 * s;
                    kreg[j] = *(const ushort8*)(K + (size_t)(qb * 77 + s) * 320 + (h + 1) * 40 + c * 8);
                }
            }
        }

        // QK^T : rows 16w.., cols 0..79 (5 frags), K-dim 64 (2 steps)
        f32x4 sacc[5] = {};
        bf16x8 qa[2];
        #pragma unroll
        for (int kt = 0; kt < 2; ++kt)
            qa[kt] = *(const bf16x8*)&Q_lds[(w * 16 + c15) * 72 + kt * 32 + khi];
        #pragma unroll
        for (int f = 0; f < 5; ++f)
            #pragma unroll
            for (int kt = 0; kt < 2; ++kt) {
                bf16x8 kb = *(const bf16x8*)&KV_lds[(f * 16 + c15) * 72 + kt * 32 + khi];
                sacc[f] = __builtin_amdgcn_mfma_f32_16x16x32_bf16(qa[kt], kb, sacc[f], 0, 0, 0);
            }

        // masked softmax (per C-row; 16-lane shuffle reduce)
        float pv[5][4];
        #pragma unroll
        for (int r = 0; r < 4; ++r) {
            float mx = -1e30f;
            #pragma unroll
            for (int f = 0; f < 5; ++f) {
                float vs = sacc[f][r] * ATT_SCALE;
                bool valid = (f < 4) || (c15 < 13);     // col = 16f + c15 < 77
                pv[f][r] = valid ? vs : -1e30f;
                mx = fmaxf(mx, pv[f][r]);
            }
            #pragma unroll
            for (int d = 1; d < 16; d <<= 1) mx = fmaxf(mx, __shfl_xor(mx, d));
            float sum = 0.f;
            #pragma unroll
            for (int f = 0; f < 5; ++f) {
                float e = (pv[f][r] > -1e29f) ? __expf(pv[f][r] - mx) : 0.f;
                pv[f][r] = e; sum += e;
            }
            #pragma unroll
            for (int d = 1; d < 16; d <<= 1) sum += __shfl_xor(sum, d);
            float inv = 1.f / sum;
            #pragma unroll
            for (int f = 0; f < 5; ++f) pv[f][r] *= inv;
        }
        #pragma unroll
        for (int r = 0; r < 4; ++r)
            #pragma unroll
            for (int f = 0; f < 5; ++f)
                P_lds[(w * 16 + rbase + r) * 104 + f * 16 + c15] = f2bf(pv[f][r]);
        __syncthreads();    // K fully consumed; P visible

        // phase B: write V into the K region
        #pragma unroll
        for (int j = 0; j < 2; ++j) {
            int idx = tid + j * 256;
            if (idx < 400) {
                int dc = idx / 10, c = idx - 10 * dc;
                *(ushort8*)&KV_lds[dc * 104 + c * 8] = vreg[j];
            }
        }
        __syncthreads();    // V visible

        if (h < 7) {        // prefetch next head's V (lands under PV)
            #pragma unroll
            for (int j = 0; j < 2; ++j) {
                int idx = tid + j * 256;
                if (idx < 400) {
                    int dc = idx / 10, c = idx - 10 * dc;
                    ushort8 v = *(const ushort8*)(Vbase + ((size_t)(h + 1) * 40 + dc) * 80 + c * 8);
                    if (c == 9) { v[5] = 0; v[6] = 0; v[7] = 0; }
                    vreg[j] = v;
                }
            }
        }

        // PV: out rows 16w.., dcols 0..47 (3 frags), K-dim 96 (3 steps)
        bf16x8 pa[3];
        #pragma unroll
        for (int kt = 0; kt < 3; ++kt)
            pa[kt] = *(const bf16x8*)&P_lds[(w * 16 + c15) * 104 + kt * 32 + khi];
        f32x4 oacc[3] = {};
        #pragma unroll
        for (int f = 0; f < 3; ++f)
            #pragma unroll
            for (int kt = 0; kt < 3; ++kt) {
                bf16x8 vb = *(const bf16x8*)&KV_lds[(f * 16 + c15) * 104 + kt * 32 + khi];
                oacc[f] = __builtin_amdgcn_mfma_f32_16x16x32_bf16(pa[kt], vb, oacc[f], 0, 0, 0);
            }
        #pragma unroll
        for (int f = 0; f < 3; ++f) {
            int col = f * 16 + c15;
            if (col < 40) {
                #pragma unroll
                for (int r = 0; r < 4; ++r)
                    AO_lds[(size_t)(w * 16 + rbase + r) * 328 + h * 40 + col] = f2bf(oacc[f][r]);
            }
        }
        __syncthreads();    // V+P consumed, AO visible; regions free for next head
    }

    // ---- out-projection: out[64x320] = AO_lds @ Wo_t^T + bias ----
    f32x4 acc[4][5] = {};
    ushort8 breg[5];
    #pragma unroll
    for (int i = 0; i < 5; ++i) {
        int idx = tid + i * 256; int n = idx >> 2, q = (idx & 3) * 8;
        breg[i] = *(const ushort8*)(Wo_t + (size_t)n * 320 + q);
    }
    for (int k = 0; k < 10; ++k) {
        if (k > 0) __syncthreads();     // prev MFMA done before overwrite
        #pragma unroll
        for (int i = 0; i < 5; ++i) {
            int idx = tid + i * 256; int n = idx >> 2, q = (idx & 3) * 8;
            *(ushort8*)&W_lds[n * 40 + q] = breg[i];
        }
        __syncthreads();
        if (k < 9) {
            int kk = (k + 1) * 32;
            #pragma unroll
            for (int i = 0; i < 5; ++i) {
                int idx = tid + i * 256; int n = idx >> 2, q = (idx & 3) * 8;
                breg[i] = *(const ushort8*)(Wo_t + (size_t)n * 320 + kk + q);
            }
        }
        bf16x8 a[4];
        #pragma unroll
        for (int mf = 0; mf < 4; ++mf)
            a[mf] = *(const bf16x8*)&AO_lds[(size_t)(mf * 16 + c15) * 328 + k * 32 + khi];
        #pragma unroll
        for (int f = 0; f < 5; ++f) {
            bf16x8 b = *(const bf16x8*)&W_lds[(w * 80 + f * 16 + c15) * 40 + khi];
            #pragma unroll
            for (int mf = 0; mf < 4; ++mf)
                acc[mf][f] = __builtin_amdgcn_mfma_f32_16x16x32_bf16(a[mf], b, acc[mf][f], 0, 0, 0);
        }
    }
    #pragma unroll
    for (int mf = 0; mf < 4; ++mf)
        #pragma unroll
        for (int f = 0; f < 5; ++f) {
            int col = w * 80 + f * 16 + c15;
            #pragma unroll
            for (int rr = 0; rr < 4; ++rr)
                out[(size_t)(bt * 4096 + t0 + mf * 16 + rbase + rr) * 320 + col]
                    = acc[mf][f][rr] + bias[col];
        }
}

// ---------------------------------------------------------------------------
extern "C" void kernel_launch(void* const* d_in, const int* in_sizes, int n_in,
                              void* d_out, int out_size, void* d_ws, size_t ws_size,
                              hipStream_t stream) {
    (void)in_sizes; (void)n_in; (void)out_size; (void)ws_size;
    const float* hs     = (const float*)d_in[0];   // (8,4096,320)
    const float* ehs    = (const float*)d_in[1];   // (8,77,768)
    const float* mapper = (const float*)d_in[2];   // (3,77,77)
    const float* Wq     = (const float*)d_in[3];   // (320,320)
    const float* Wk     = (const float*)d_in[4];   // (768,320)
    const float* Wv     = (const float*)d_in[5];   // (768,320)
    const float* Wo     = (const float*)d_in[6];   // (320,320)
    const float* bo     = (const float*)d_in[7];   // (320,)
    float* out = (float*)d_out;

    ushort* ws   = (ushort*)d_ws;
    ushort* Wq_t = ws;                             // 320*320
    ushort* Wk_t = Wq_t + 320 * 320;               // 320*768
    ushort* Wv_t = Wk_t + 320 * 768;
    ushort* Wo_t = Wv_t + 320 * 768;               // 320*320
    ushort* Qb   = Wo_t + 320 * 320;               // 20480*320
    ushort* Kb   = Qb + 20480 * 320;               // 616*320
    ushort* VVt  = Kb + 616 * 320;                 // 8*320*80  (V^T, s padded 80)
    ushort* VPt  = VVt + 8 * 320 * 80;             // 3*320*80  (V'^T)
    float*  part = (float*)(VPt + 3 * 320 * 80);   // 16*640*320 f32 = 13.1 MB

    transpose_all<<<680, 256, 0, stream>>>(Wq, Wk, Wv, Wo, Wq_t, Wk_t, Wv_t, Wo_t);
    gemm_qkv<<<480, 256, 0, stream>>>(hs, Wq_t, ehs, Wk_t, Wv_t, Qb, part);
    kv_reduce<<<dim3(770, 2), 256, 0, stream>>>(part, Kb, VVt);
    vprime_k<<<231, 320, 0, stream>>>(mapper, VVt, VPt);
    attn_out_k<<<dim3(64, 8), 256, 0, stream>>>(Qb, Kb, VVt, VPt, Wo_t, bo, out);
}